// Round 1
// 62.463 us; speedup vs baseline: 1.0001x; 1.0001x over previous
//
#include <hip/hip_runtime.h>

#define ROWN 512
constexpr float MARGIN = 1.0f;
constexpr float NEG_INF = -1e30f;
// Validity key: a constant-pattern poison fill X yields tag==X, data==X and
// X == (X ^ KEY) is impossible for KEY != 0, so poisoned slots never validate.
constexpr unsigned long long TAG_KEY = 0x9E3779B97F4A7C15ull;

struct alignas(16) RowSlot {
    unsigned long long data;  // [31:0] row_sum (f32 bits), [63:32] pair count
    unsigned long long tag;   // data ^ TAG_KEY, store-released after data
};

// R6: single-dispatch fusion of R5's rows+final. Row phase is byte-identical
// to R5's pmrl_rows (proven, 64→62.4us lineage). Cross-block handoff is
// store-only scoped atomics + a validated-tag spin in block 0 — no grid sync,
// no contended RMW (the causes of the earlier fused regressions), and no
// init/memset node needed (tag validation is poison-proof).
__global__ __launch_bounds__(256) void pmrl_fused(const float* __restrict__ scores,
                                                  const int* __restrict__ labels,
                                                  RowSlot* __restrict__ slots,
                                                  float* __restrict__ out) {
    __shared__ float pos_s[ROWN];
    __shared__ float neg_s[ROWN + 8];   // pad to multiple of 8 with -inf
    __shared__ int cnts[2];             // [0]=pos count, [1]=neg count
    __shared__ float wsum[4];

    const int row  = blockIdx.x;
    const int t    = threadIdx.x;
    const int lane = t & 63;

    if (t < 2) cnts[t] = 0;
    __syncthreads();

    const float* s = scores + (size_t)row * ROWN;
    const int*   l = labels + (size_t)row * ROWN;

    // 8B/lane vectorized stage; compaction order is irrelevant to the sum.
    const float2 v2 = ((const float2*)s)[t];
    const int2   i2 = ((const int2*)l)[t];
    const float vv[2] = {v2.x, v2.y};
    const int   ll[2] = {i2.x, i2.y};

    #pragma unroll
    for (int r = 0; r < 2; ++r) {
        const float v  = vv[r];
        const int  lab = ll[r];
        const bool isp = (lab == 1);
        const bool isn = (lab == 0);
        const unsigned long long bp = __ballot(isp);
        const unsigned long long bn = __ballot(isn);
        const unsigned long long ltmask = (1ull << lane) - 1ull;
        const int pp = __popcll(bp & ltmask);
        const int pn = __popcll(bn & ltmask);
        int basep = 0, basen = 0;
        if (lane == 0) {
            basep = atomicAdd(&cnts[0], __popcll(bp));
            basen = atomicAdd(&cnts[1], __popcll(bn));
        }
        basep = __shfl(basep, 0, 64);
        basen = __shfl(basen, 0, 64);
        if (isp) pos_s[basep + pp] = v;
        if (isn) neg_s[basen + pn] = v;
    }
    __syncthreads();

    const int P = cnts[0];
    const int Q = cnts[1];

    // pad negatives to a multiple of 8 with -inf so padded lanes contribute 0
    const int pad = (8 - (Q & 7)) & 7;
    if (t < pad) neg_s[Q + t] = NEG_INF;
    __syncthreads();
    const int Q8 = (Q + 7) >> 3;

    float acc = 0.0f;
    const float4* neg4 = (const float4*)neg_s;
    for (int i = t; i < P; i += 256) {
        const float c = MARGIN - pos_s[i];
        float a0 = 0.f, a1 = 0.f, a2 = 0.f, a3 = 0.f;
        for (int j = 0; j < Q8; ++j) {
            // wave-uniform addresses -> ds_read_b128 broadcast, conflict-free
            const float4 n0 = neg4[2 * j];
            const float4 n1 = neg4[2 * j + 1];
            a0 += fmaxf(c + n0.x, 0.0f);
            a1 += fmaxf(c + n0.y, 0.0f);
            a2 += fmaxf(c + n0.z, 0.0f);
            a3 += fmaxf(c + n0.w, 0.0f);
            a0 += fmaxf(c + n1.x, 0.0f);
            a1 += fmaxf(c + n1.y, 0.0f);
            a2 += fmaxf(c + n1.z, 0.0f);
            a3 += fmaxf(c + n1.w, 0.0f);
        }
        acc += (a0 + a1) + (a2 + a3);
    }

    // wave(64) shuffle reduction, then 4-wave combine
    #pragma unroll
    for (int off = 32; off > 0; off >>= 1) acc += __shfl_down(acc, off, 64);
    if (lane == 0) wsum[t >> 6] = acc;
    __syncthreads();

    if (t == 0) {
        const float total  = (wsum[0] + wsum[1]) + (wsum[2] + wsum[3]);
        const unsigned prs = (unsigned)(P * Q);
        const unsigned long long d =
            (unsigned long long)__float_as_uint(total) |
            ((unsigned long long)prs << 32);
        // data relaxed, tag released: a valid tag implies the data word is
        // the one published with it (agent scope = device-visible).
        __hip_atomic_store(&slots[row].data, d, __ATOMIC_RELAXED,
                           __HIP_MEMORY_SCOPE_AGENT);
        __hip_atomic_store(&slots[row].tag, d ^ TAG_KEY, __ATOMIC_RELEASE,
                           __HIP_MEMORY_SCOPE_AGENT);
    }

    if (blockIdx.x != 0) return;

    // ---- finalizer: block 0 only. 256 threads each own rows t and t+256.
    // Operation order matches R5's pmrl_final exactly -> bit-identical output.
    __shared__ double dsum[4];
    __shared__ unsigned long long dcnt[4];

    double sd = 0.0;
    unsigned long long pc = 0;
    #pragma unroll
    for (int rr = 0; rr < 2; ++rr) {
        const int r = t + rr * 256;
        unsigned long long tg, d;
        while (true) {
            tg = __hip_atomic_load(&slots[r].tag, __ATOMIC_ACQUIRE,
                                   __HIP_MEMORY_SCOPE_AGENT);
            d  = __hip_atomic_load(&slots[r].data, __ATOMIC_RELAXED,
                                   __HIP_MEMORY_SCOPE_AGENT);
            if (tg == (d ^ TAG_KEY)) break;
            __builtin_amdgcn_s_sleep(2);   // be polite to L2 while spinning
        }
        sd += (double)__uint_as_float((unsigned)(d & 0xffffffffull));
        pc += (d >> 32);
    }
    #pragma unroll
    for (int off = 32; off > 0; off >>= 1) {
        sd += __shfl_down(sd, off, 64);
        pc += __shfl_down(pc, off, 64);
    }
    if (lane == 0) { dsum[t >> 6] = sd; dcnt[t >> 6] = pc; }
    __syncthreads();
    if (t == 0) {
        const double total = (dsum[0] + dsum[1]) + (dsum[2] + dsum[3]);
        const unsigned long long n = dcnt[0] + dcnt[1] + dcnt[2] + dcnt[3];
        out[0] = (n > 0ull) ? (float)(total / (double)n) : 0.0f;
    }
}

extern "C" void kernel_launch(void* const* d_in, const int* in_sizes, int n_in,
                              void* d_out, int out_size, void* d_ws, size_t ws_size,
                              hipStream_t stream) {
    const float* scores = (const float*)d_in[0];
    const int*   labels = (const int*)d_in[1];
    float*       out    = (float*)d_out;
    RowSlot*     slots  = (RowSlot*)d_ws;   // 512 * 16 B = 8 KiB

    pmrl_fused<<<ROWN, 256, 0, stream>>>(scores, labels, slots, out);
}